// Round 12
// baseline (728.667 us; speedup 1.0000x reference)
//
#include <hip/hip_runtime.h>
#include <math.h>

#define T_TOK 8192
#define HDIM 2048
#define IDIM 1024
#define NE 8

typedef __attribute__((ext_vector_type(8))) short short8;
typedef __attribute__((ext_vector_type(4))) float f32x4;
typedef unsigned short u16;

__device__ inline u16 f2bf(float f) {
  unsigned u = __builtin_bit_cast(unsigned, f);
  u += 0x7fffu + ((u >> 16) & 1);  // RNE
  return (u16)(u >> 16);
}
__device__ inline float bf2f(u16 u) {
  unsigned v = (unsigned)u << 16;
  return __builtin_bit_cast(float, v);
}

// async global->LDS, 16B/lane. LDS dest = wave-uniform base + lane*16.
__device__ inline void gl_lds(const u16* g, u16* l) {
  __builtin_amdgcn_global_load_lds((const __attribute__((address_space(1))) unsigned int*)g,
                                   (__attribute__((address_space(3))) unsigned int*)l, 16, 0, 0);
}

#define MFMA(a, b, c) __builtin_amdgcn_mfma_f32_16x16x32_bf16((a), (b), (c), 0, 0, 0)

// BK=64 tiles: [row][64] u16 rows (128 B). Granule position p of row R holds
// source k-granule p ^ (R&7) (swizzle applied on the GLOBAL source address;
// LDS stays linear for gl_lds). Frag read slice s, lane-group g: position
// (4s+g) ^ (R&7); 16-lane frag groups touch each bank-group exactly 2x (free).

// ---------- ws layout ----------
// 0       meta: cnt[8] cursor[8] offsets[8] (u32)
// 256     slot_token u16[2T]  (32 KB)
// 33024   slot_w    f32[2T]   (64 KB)
// 98560   tok2slot  u16[2T]   (32 KB)   -> ends 131328
// 132096  xbf  bf16[T*H]      (33.5 MB)
// ACT     act  bf16[2T*I]     (33.5 MB)  (sel/wt stashed here pre-k4)
// WGT     wgT / wuT           (67 MB)    -> y bf16[2T*H] after k4 (exact fit)
// WDT     wdT                 (33.5 MB)  total 167,904,256 (proven R5)

// ---------------- K0: x->bf16 + zero counters ----------------
__global__ __launch_bounds__(256) void k0_init(const float* __restrict__ x,
                                               u16* __restrict__ xb,
                                               unsigned* __restrict__ meta) {
  size_t i = (size_t)blockIdx.x * blockDim.x + threadIdx.x;
  size_t total = (size_t)T_TOK * HDIM;
  size_t stride = (size_t)gridDim.x * 256 * 8;
  for (size_t p = i * 8; p < total; p += stride) {
    float4 v0 = *(const float4*)(x + p);
    float4 v1 = *(const float4*)(x + p + 4);
    short8 o;
    o[0] = f2bf(v0.x); o[1] = f2bf(v0.y); o[2] = f2bf(v0.z); o[3] = f2bf(v0.w);
    o[4] = f2bf(v1.x); o[5] = f2bf(v1.y); o[6] = f2bf(v1.z); o[7] = f2bf(v1.w);
    *(short8*)(xb + p) = o;
  }
  if (blockIdx.x == 0 && threadIdx.x < 24) meta[threadIdx.x] = 0;
}

// ---------------- KT: weight transpose+cvt: dst[n][k] = bf16(src[k][n]) ----------------
__global__ __launch_bounds__(256) void kt_transpose2(const float* __restrict__ srcA,
                                                     u16* __restrict__ dstA,
                                                     const float* __restrict__ srcB,
                                                     u16* __restrict__ dstB, int K, int N) {
  __shared__ u16 t[64][72];
  int z = blockIdx.z;
  const float* src = (z < NE ? srcA : srcB) + (size_t)(z & 7) * K * N;
  u16* dst = (z < NE ? dstA : dstB) + (size_t)(z & 7) * K * N;
  int nb = blockIdx.x * 64, kb = blockIdx.y * 64;
  int tid = threadIdx.x;
  int lk = tid >> 4, ln = (tid & 15) * 4;
#pragma unroll
  for (int p = 0; p < 4; ++p) {
    int k = lk + 16 * p;
    float4 v = *(const float4*)(src + (size_t)(kb + k) * N + nb + ln);
    t[ln + 0][k] = f2bf(v.x);
    t[ln + 1][k] = f2bf(v.y);
    t[ln + 2][k] = f2bf(v.z);
    t[ln + 3][k] = f2bf(v.w);
  }
  __syncthreads();
  int n = tid >> 2, c = tid & 3;
  short8 o0 = *(const short8*)&t[n][c * 16];
  short8 o1 = *(const short8*)&t[n][c * 16 + 8];
  u16* d = dst + (size_t)(nb + n) * K + kb + c * 16;
  *(short8*)d = o0;
  *(short8*)(d + 8) = o1;
}

// ---------------- K1: router ----------------
__global__ __launch_bounds__(256) void k1_router(const float* __restrict__ x,
                                                 const float* __restrict__ wgate,
                                                 float* __restrict__ logits_out,
                                                 char* __restrict__ sel,
                                                 float* __restrict__ wt,
                                                 unsigned* __restrict__ cnt) {
  int wave = threadIdx.x >> 6;
  int lane = threadIdx.x & 63;
  int t = blockIdx.x * 4 + wave;
  float acc[NE];
#pragma unroll
  for (int e = 0; e < NE; ++e) acc[e] = 0.f;
  const float4* xr = (const float4*)(x + (size_t)t * HDIM);
#pragma unroll
  for (int c = 0; c < HDIM / 256; ++c) {
    float4 xv = xr[c * 64 + lane];
    int h = (c * 64 + lane) * 4;
    const float xs[4] = {xv.x, xv.y, xv.z, xv.w};
#pragma unroll
    for (int j = 0; j < 4; ++j) {
      const float* wrow = wgate + (size_t)(h + j) * NE;
#pragma unroll
      for (int e = 0; e < NE; ++e) acc[e] += xs[j] * wrow[e];
    }
  }
#pragma unroll
  for (int e = 0; e < NE; ++e) {
    float v = acc[e];
#pragma unroll
    for (int off = 32; off; off >>= 1) v += __shfl_xor(v, off, 64);
    acc[e] = v;
  }
  if (lane == 0) {
    float m = acc[0];
#pragma unroll
    for (int e = 0; e < NE; ++e) {
      logits_out[(size_t)t * NE + e] = acc[e];
      m = fmaxf(m, acc[e]);
    }
    float p[NE];
#pragma unroll
    for (int e = 0; e < NE; ++e) p[e] = expf(acc[e] - m);
    int b0 = 0;
    float v0 = p[0];
#pragma unroll
    for (int e = 1; e < NE; ++e)
      if (p[e] > v0) { v0 = p[e]; b0 = e; }
    int b1 = -1;
    float v1 = -1.f;
#pragma unroll
    for (int e = 0; e < NE; ++e)
      if (e != b0 && p[e] > v1) { v1 = p[e]; b1 = e; }
    float denom = v0 + v1;
    sel[t * 2 + 0] = (char)b0;
    sel[t * 2 + 1] = (char)b1;
    wt[t * 2 + 0] = v0 / denom;
    wt[t * 2 + 1] = v1 / denom;
    atomicAdd(&cnt[b0], 1u);
    atomicAdd(&cnt[b1], 1u);
  }
}

// ---------------- K2 / K3 ----------------
__global__ void k2_prefix(const unsigned* __restrict__ cnt, unsigned* __restrict__ offsets,
                          unsigned* __restrict__ cursor) {
  if (threadIdx.x == 0) {
    unsigned s = 0;
    for (int e = 0; e < NE; ++e) {
      offsets[e] = s;
      s += cnt[e];
    }
  }
  if (threadIdx.x < NE) cursor[threadIdx.x] = 0;
}

__global__ __launch_bounds__(256) void k3_assign(const char* __restrict__ sel,
                                                 const float* __restrict__ wt,
                                                 const unsigned* __restrict__ offsets,
                                                 unsigned* __restrict__ cursor,
                                                 u16* __restrict__ slot_token,
                                                 float* __restrict__ slot_w,
                                                 u16* __restrict__ tok2slot) {
  int t = blockIdx.x * 256 + threadIdx.x;
#pragma unroll
  for (int k = 0; k < 2; ++k) {
    int e = sel[t * 2 + k];
    unsigned p = atomicAdd(&cursor[e], 1u);
    unsigned s = offsets[e] + p;
    slot_token[s] = (u16)t;
    slot_w[s] = wt[t * 2 + k];
    tok2slot[t * 2 + k] = (u16)s;
  }
}

// Bijective XCD swizzle for 64x8x8 = 4096-block grids (8 XCDs, 512/XCD).
__device__ inline void xcd_decomp(int& bx, int& by, int& be) {
  unsigned bid = blockIdx.x + 64u * (blockIdx.y + 8u * blockIdx.z);
  unsigned swz = (bid & 7u) * 512u + (bid >> 3);
  bx = swz & 63u;
  unsigned rem = swz >> 6;
  by = rem & 7u;
  be = rem >> 3;
}

// Per-phase compute tail: barrier -> lgkmcnt(0) -> sched_barrier (rule 18)
#define PHASE_SYNC()                                  \
  __builtin_amdgcn_s_barrier();                       \
  asm volatile("s_waitcnt lgkmcnt(0)" ::: "memory");  \
  __builtin_amdgcn_sched_barrier(0)

// ---------------- K4: 8-phase MFMA gate+up + silu -> bf16 act ----------------
// tile 256m x (128g + 128u)n, BK=64, 512 thr = 8 waves (2M x 4N), dbuf LDS 128KB.
// 4 phases per K-tile: (mh,s) quadrants, 16 MFMA each. Stage A(t+1) at P0,
// B(t+1) at P1, awaited (vmcnt 0, ~2-3 phase lead) at P3.
__global__ __launch_bounds__(512, 1) void k4_gateup(
    const u16* __restrict__ xb, const u16* __restrict__ wgT, const u16* __restrict__ wuT,
    const u16* __restrict__ slot_token, const unsigned* __restrict__ offsets,
    const unsigned* __restrict__ cnt, u16* __restrict__ act) {
  int bx, by, e;
  xcd_decomp(bx, by, e);
  unsigned n = cnt[e];
  unsigned row0 = (unsigned)bx * 256;
  if (row0 >= n) return;
  unsigned base = offsets[e];
  int col0 = by * 128;

  __shared__ __align__(16) u16 As[2][256 * 64];   // 64 KB
  __shared__ __align__(16) u16 Bgs[2][128 * 64];  // 32 KB
  __shared__ __align__(16) u16 Bus[2][128 * 64];  // 32 KB

  int tid = threadIdx.x;
  int w = tid >> 6, l = tid & 63;
  int wr = w >> 2, wc = w & 3;
  int lr = l & 15, g = l >> 4;
  int lrow = l >> 3, lg = l & 7;

  // A staging: 4 gl_lds/thread per K-tile (2 halves x 2 chunks); rows gathered.
  const u16* aptr[4];
  int adst[4];
#pragma unroll
  for (int h = 0; h < 2; ++h)
#pragma unroll
    for (int i = 0; i < 2; ++i) {
      int c = 2 * w + i;
      int R = h * 128 + 8 * c + lrow;
      unsigned grow = row0 + (unsigned)R;
      unsigned slot = base + (grow < n ? grow : 0);
      aptr[h * 2 + i] = xb + (size_t)slot_token[slot] * HDIM + 8 * (lg ^ (R & 7));
      adst[h * 2 + i] = h * 8192 + c * 512 + l * 8;
    }
  // B staging: 2 gl_lds/thread per matrix per K-tile.
  const u16 *bgp[2], *bup[2];
  int bdst[2];
#pragma unroll
  for (int i = 0; i < 2; ++i) {
    int c = 2 * w + i;
    int R = 8 * c + lrow;
    size_t o = (size_t)e * HDIM * IDIM + (size_t)(col0 + R) * HDIM + 8 * (lg ^ (R & 7));
    bgp[i] = wgT + o;
    bup[i] = wuT + o;
    bdst[i] = c * 512 + l * 8;
  }

  int afo[8][2], bfo[2][2];
#pragma unroll
  for (int mf = 0; mf < 8; ++mf) {
    int R = wr * 128 + mf * 16 + lr;
#pragma unroll
    for (int s = 0; s < 2; ++s) afo[mf][s] = R * 64 + 8 * ((4 * s + g) ^ (R & 7));
  }
#pragma unroll
  for (int nf = 0; nf < 2; ++nf) {
    int R = wc * 32 + nf * 16 + lr;
#pragma unroll
    for (int s = 0; s < 2; ++s) bfo[nf][s] = R * 64 + 8 * ((4 * s + g) ^ (R & 7));
  }

  f32x4 ag[8][2] = {};
  f32x4 au[8][2] = {};

#define K4_STAGE_A(k0, buf)                         \
  {                                                 \
    _Pragma("unroll") for (int j = 0; j < 4; ++j)   \
        gl_lds(aptr[j] + (k0), &As[buf][adst[j]]);  \
  }
#define K4_STAGE_B(k0, buf)                          \
  {                                                  \
    _Pragma("unroll") for (int i = 0; i < 2; ++i) {  \
      gl_lds(bgp[i] + (k0), &Bgs[buf][bdst[i]]);     \
      gl_lds(bup[i] + (k0), &Bus[buf][bdst[i]]);     \
    }                                                \
  }

  K4_STAGE_A(0, 0);
  K4_STAGE_B(0, 0);
  asm volatile("s_waitcnt vmcnt(0)" ::: "memory");
  __builtin_amdgcn_s_barrier();

  const int NT = HDIM / 64;
  for (int t = 0; t < NT; ++t) {
    int cur = t & 1;
    int kn = (t + 1) * 64;
    short8 av[4], bg[2], bu[2];

    // ---- P0: read A(mh0,s0)+B(s0); stage A(t+1)
#pragma unroll
    for (int i = 0; i < 4; ++i) av[i] = *(const short8*)&As[cur][afo[i][0]];
#pragma unroll
    for (int nf = 0; nf < 2; ++nf) {
      bg[nf] = *(const short8*)&Bgs[cur][bfo[nf][0]];
      bu[nf] = *(const short8*)&Bus[cur][bfo[nf][0]];
    }
    if (t + 1 < NT) K4_STAGE_A(kn, cur ^ 1);
    PHASE_SYNC();
    __builtin_amdgcn_s_setprio(1);
#pragma unroll
    for (int nf = 0; nf < 2; ++nf)
#pragma unroll
      for (int i = 0; i < 4; ++i) {
        ag[i][nf] = MFMA(av[i], bg[nf], ag[i][nf]);
        au[i][nf] = MFMA(av[i], bu[nf], au[i][nf]);
      }
    __builtin_amdgcn_s_setprio(0);
    __builtin_amdgcn_s_barrier();

    // ---- P1: read A(mh1,s0), reuse B(s0); stage B(t+1)
#pragma unroll
    for (int i = 0; i < 4; ++i) av[i] = *(const short8*)&As[cur][afo[4 + i][0]];
    if (t + 1 < NT) K4_STAGE_B(kn, cur ^ 1);
    PHASE_SYNC();
    __builtin_amdgcn_s_setprio(1);
#pragma unroll
    for (int nf = 0; nf < 2; ++nf)
#pragma unroll
      for (int i = 0; i < 4; ++i) {
        ag[4 + i][nf] = MFMA(av[i], bg[nf], ag[4 + i][nf]);
        au[4 + i][nf] = MFMA(av[i], bu[nf], au[4 + i][nf]);
      }
    __builtin_amdgcn_s_setprio(0);
    __builtin_amdgcn_s_barrier();

    // ---- P2: read A(mh0,s1)+B(s1)
#pragma unroll
    for (int i = 0; i < 4; ++i) av[i] = *(const short8*)&As[cur][afo[i][1]];
#pragma unroll
    for (int nf = 0; nf < 2; ++nf) {
      bg[nf] = *(const short8*)&Bgs[cur][bfo[nf][1]];
      bu[nf] = *(const short8*)&Bus[cur][bfo[nf][1]];
    }
    PHASE_SYNC();
    __builtin_amdgcn_s_setprio(1);
#pragma unroll
    for (int nf = 0; nf < 2; ++nf)
#pragma unroll
      for (int i = 0; i < 4; ++i) {
        ag[i][nf] = MFMA(av[i], bg[nf], ag[i][nf]);
        au[i][nf] = MFMA(av[i], bu[nf], au[i][nf]);
      }
    __builtin_amdgcn_s_setprio(0);
    __builtin_amdgcn_s_barrier();

    // ---- P3: read A(mh1,s1); await tile t+1 (issued P0/P1, ~2-3 phase lead)
#pragma unroll
    for (int i = 0; i < 4; ++i) av[i] = *(const short8*)&As[cur][afo[4 + i][1]];
    if (t + 1 < NT) asm volatile("s_waitcnt vmcnt(0)" ::: "memory");
    PHASE_SYNC();
    __builtin_amdgcn_s_setprio(1);
#pragma unroll
    for (int nf = 0; nf < 2; ++nf)
#pragma unroll
      for (int i = 0; i < 4; ++i) {
        ag[4 + i][nf] = MFMA(av[i], bg[nf], ag[4 + i][nf]);
        au[4 + i][nf] = MFMA(av[i], bu[nf], au[4 + i][nf]);
      }
    __builtin_amdgcn_s_setprio(0);
    __builtin_amdgcn_s_barrier();
  }
#undef K4_STAGE_A
#undef K4_STAGE_B

  unsigned rows_left = n - row0;
#pragma unroll
  for (int mf = 0; mf < 8; ++mf)
#pragma unroll
    for (int nf = 0; nf < 2; ++nf)
#pragma unroll
      for (int j = 0; j < 4; ++j) {
        int rin = wr * 128 + mf * 16 + 4 * g + j;
        if ((unsigned)rin < rows_left) {
          size_t s = base + row0 + rin;
          int col = col0 + wc * 32 + nf * 16 + lr;
          float gg = ag[mf][nf][j];
          float uu = au[mf][nf][j];
          float v = (gg / (1.f + expf(-gg))) * uu;
          act[s * IDIM + col] = f2bf(v);
        }
      }
}

// ---------------- K5: 8-phase MFMA down -> bf16 y ----------------
// tile 256m x 256n, BK=64, 512 thr = 8 waves (2M x 4N), dbuf LDS 128KB (m201 geometry).
__global__ __launch_bounds__(512, 1) void k5_down(
    const u16* __restrict__ act, const u16* __restrict__ wdT,
    const unsigned* __restrict__ offsets, const unsigned* __restrict__ cnt,
    u16* __restrict__ y) {
  int bx, by, e;
  xcd_decomp(bx, by, e);
  unsigned n = cnt[e];
  unsigned row0 = (unsigned)bx * 256;
  if (row0 >= n) return;
  unsigned base = offsets[e];
  int col0 = by * 256;

  __shared__ __align__(16) u16 As[2][256 * 64];  // 64 KB
  __shared__ __align__(16) u16 Bs[2][256 * 64];  // 64 KB

  int tid = threadIdx.x;
  int w = tid >> 6, l = tid & 63;
  int wr = w >> 2, wc = w & 3;
  int lr = l & 15, g = l >> 4;
  int lrow = l >> 3, lg = l & 7;

  const u16* aptr[4];
  const u16* bptr[4];
  int tdst[4];
#pragma unroll
  for (int h = 0; h < 2; ++h)
#pragma unroll
    for (int i = 0; i < 2; ++i) {
      int c = 2 * w + i;
      int R = h * 128 + 8 * c + lrow;
      unsigned grow = row0 + (unsigned)R;
      unsigned slot = base + (grow < n ? grow : 0);
      aptr[h * 2 + i] = act + (size_t)slot * IDIM + 8 * (lg ^ (R & 7));
      bptr[h * 2 + i] =
          wdT + (size_t)e * IDIM * HDIM + (size_t)(col0 + R) * IDIM + 8 * (lg ^ (R & 7));
      tdst[h * 2 + i] = h * 8192 + c * 512 + l * 8;
    }

  int afo[8][2], bfo[4][2];
#pragma unroll
  for (int mf = 0; mf < 8; ++mf) {
    int R = wr * 128 + mf * 16 + lr;
#pragma unroll
    for (int s = 0; s < 2; ++s) afo[mf][s] = R * 64 + 8 * ((4 * s + g) ^ (R & 7));
  }
#pragma unroll
  for (int nf = 0; nf < 4; ++nf) {
    int R = wc * 64 + nf * 16 + lr;
#pragma unroll
    for (int s = 0; s < 2; ++s) bfo[nf][s] = R * 64 + 8 * ((4 * s + g) ^ (R & 7));
  }

  f32x4 acc[8][4] = {};

#define K5_STAGE_A(k0, buf)                         \
  {                                                 \
    _Pragma("unroll") for (int j = 0; j < 4; ++j)   \
        gl_lds(aptr[j] + (k0), &As[buf][tdst[j]]);  \
  }
#define K5_STAGE_B(k0, buf)                         \
  {                                                 \
    _Pragma("unroll") for (int j = 0; j < 4; ++j)   \
        gl_lds(bptr[j] + (k0), &Bs[buf][tdst[j]]);  \
  }

  K5_STAGE_A(0, 0);
  K5_STAGE_B(0, 0);
  asm volatile("s_waitcnt vmcnt(0)" ::: "memory");
  __builtin_amdgcn_s_barrier();

  const int NT = IDIM / 64;
  for (int t = 0; t < NT; ++t) {
    int cur = t & 1;
    int kn = (t + 1) * 64;
    short8 av[4], bv[4];

    // ---- P0: read A(mh0,s0)+B(s0); stage A(t+1)
#pragma unroll
    for (int i = 0; i < 4; ++i) av[i] = *(const short8*)&As[cur][afo[i][0]];
#pragma unroll
    for (int nf = 0; nf < 4; ++nf) bv[nf] = *(const short8*)&Bs[cur][bfo[nf][0]];
    if (t + 1 < NT) K5_STAGE_A(kn, cur ^ 1);
    PHASE_SYNC();
    __builtin_amdgcn_s_setprio(1);
#pragma unroll
    for (int nf = 0; nf < 4; ++nf)
#pragma unroll
      for (int i = 0; i < 4; ++i) acc[i][nf] = MFMA(av[i], bv[nf], acc[i][nf]);
    __builtin_amdgcn_s_setprio(0);
    __builtin_amdgcn_s_barrier();

    // ---- P1: read A(mh1,s0), reuse B(s0); stage B(t+1)
#pragma unroll
    for (int i = 0; i < 4; ++i) av[i] = *(const short8*)&As[cur][afo[4 + i][0]];
    if (t + 1 < NT) K5_STAGE_B(kn, cur ^ 1);
    PHASE_SYNC();
    __builtin_amdgcn_s_setprio(1);
#pragma unroll
    for (int nf = 0; nf < 4; ++nf)
#pragma unroll
      for (int i = 0; i < 4; ++i) acc[4 + i][nf] = MFMA(av[i], bv[nf], acc[4 + i][nf]);
    __builtin_amdgcn_s_setprio(0);
    __builtin_amdgcn_s_barrier();

    // ---- P2: read A(mh0,s1)+B(s1)
#pragma unroll
    for (int i = 0; i < 4; ++i) av[i] = *(const short8*)&As[cur][afo[i][1]];
#pragma unroll
    for (int nf = 0; nf < 4; ++nf) bv[nf] = *(const short8*)&Bs[cur][bfo[nf][1]];
    PHASE_SYNC();
    __builtin_amdgcn_s_setprio(1);
#pragma unroll
    for (int nf = 0; nf < 4; ++nf)
#pragma unroll
      for (int i = 0; i < 4; ++i) acc[i][nf] = MFMA(av[i], bv[nf], acc[i][nf]);
    __builtin_amdgcn_s_setprio(0);
    __builtin_amdgcn_s_barrier();

    // ---- P3: read A(mh1,s1); await tile t+1
#pragma unroll
    for (int i = 0; i < 4; ++i) av[i] = *(const short8*)&As[cur][afo[4 + i][1]];
    if (t + 1 < NT) asm volatile("s_waitcnt vmcnt(0)" ::: "memory");
    PHASE_SYNC();
    __builtin_amdgcn_s_setprio(1);
#pragma unroll
    for (int nf = 0; nf < 4; ++nf)
#pragma unroll
      for (int i = 0; i < 4; ++i) acc[4 + i][nf] = MFMA(av[i], bv[nf], acc[4 + i][nf]);
    __builtin_amdgcn_s_setprio(0);
    __builtin_amdgcn_s_barrier();
  }
#undef K5_STAGE_A
#undef K5_STAGE_B

  unsigned rows_left = n - row0;
#pragma unroll
  for (int mf = 0; mf < 8; ++mf)
#pragma unroll
    for (int j = 0; j < 4; ++j) {
      int rin = wr * 128 + mf * 16 + 4 * g + j;
      if ((unsigned)rin < rows_left) {
        size_t s = base + row0 + rin;
        u16* yrow = y + s * HDIM + col0 + wc * 64 + lr;
#pragma unroll
        for (int nf = 0; nf < 4; ++nf) yrow[nf * 16] = f2bf(acc[mf][nf][j]);
      }
    }
}

// ---------------- K6: combine out[t] = w0*y[s0] + w1*y[s1] ----------------
__global__ __launch_bounds__(256) void k6_combine(const u16* __restrict__ y,
                                                  const u16* __restrict__ tok2slot,
                                                  const float* __restrict__ slot_w,
                                                  float* __restrict__ out) {
  unsigned idx = blockIdx.x * 256 + threadIdx.x;
  int t = idx >> 8;
  int off = (idx & 255) * 8;
  int s0 = tok2slot[t * 2 + 0];
  int s1 = tok2slot[t * 2 + 1];
  float w0 = slot_w[s0];
  float w1 = slot_w[s1];
  short8 a = *(const short8*)(y + (size_t)s0 * HDIM + off);
  short8 b = *(const short8*)(y + (size_t)s1 * HDIM + off);
  float* o = out + (size_t)t * HDIM + off;
  float4 o0, o1;
  o0.x = w0 * bf2f((u16)a[0]) + w1 * bf2f((u16)b[0]);
  o0.y = w0 * bf2f((u16)a[1]) + w1 * bf2f((u16)b[1]);
  o0.z = w0 * bf2f((u16)a[2]) + w1 * bf2f((u16)b[2]);
  o0.w = w0 * bf2f((u16)a[3]) + w1 * bf2f((u16)b[3]);
  o1.x = w0 * bf2f((u16)a[4]) + w1 * bf2f((u16)b[4]);
  o1.y = w0 * bf2f((u16)a[5]) + w1 * bf2f((u16)b[5]);
  o1.z = w0 * bf2f((u16)a[6]) + w1 * bf2f((u16)b[6]);
  o1.w = w0 * bf2f((u16)a[7]) + w1 * bf2f((u16)b[7]);
  *(float4*)o = o0;
  *(float4*)(o + 4) = o1;
}

extern "C" void kernel_launch(void* const* d_in, const int* in_sizes, int n_in,
                              void* d_out, int out_size, void* d_ws, size_t ws_size,
                              hipStream_t stream) {
  const float* x = (const float*)d_in[0];
  const float* wgate = (const float*)d_in[1];
  const float* wg = (const float*)d_in[2];
  const float* wu = (const float*)d_in[3];
  const float* wd = (const float*)d_in[4];
  float* out = (float*)d_out;
  float* logits = out + (size_t)T_TOK * HDIM;

  const size_t XBF_OFF = 132096;
  const size_t ACT_OFF = XBF_OFF + (size_t)T_TOK * HDIM * 2;
  const size_t WGT_OFF = ACT_OFF + (size_t)2 * T_TOK * IDIM * 2;
  const size_t WUT_OFF = WGT_OFF + (size_t)NE * HDIM * IDIM * 2;
  const size_t WDT_OFF = WUT_OFF + (size_t)NE * HDIM * IDIM * 2;
  const size_t NEED_T3 = WDT_OFF + (size_t)NE * IDIM * HDIM * 2;  // 167,904,256 (proven R5)
  if (ws_size < NEED_T3) return;  // loud failure

  char* ws = (char*)d_ws;
  unsigned* meta = (unsigned*)ws;
  unsigned* cnt = meta + 0;
  unsigned* cursor = meta + 8;
  unsigned* offsets = meta + 16;
  u16* slot_token = (u16*)(ws + 256);
  float* slot_w = (float*)(ws + 33024);
  u16* tok2slot = (u16*)(ws + 98560);
  u16* xbf = (u16*)(ws + XBF_OFF);
  u16* act = (u16*)(ws + ACT_OFF);
  u16* wgT = (u16*)(ws + WGT_OFF);
  u16* wuT = (u16*)(ws + WUT_OFF);
  u16* wdT = (u16*)(ws + WDT_OFF);
  u16* y = (u16*)(ws + WGT_OFF);  // reuses wgT+wuT (dead after k4)
  char* sel = (char*)act;         // dead before k4 writes act
  float* wt = (float*)((char*)act + 16384);

  k0_init<<<2048, 256, 0, stream>>>(x, xbf, meta);
  kt_transpose2<<<dim3(IDIM / 64, HDIM / 64, 2 * NE), 256, 0, stream>>>(wg, wgT, wu, wuT,
                                                                        HDIM, IDIM);
  kt_transpose2<<<dim3(HDIM / 64, IDIM / 64, NE), 256, 0, stream>>>(wd, wdT, wd, wdT,
                                                                    IDIM, HDIM);
  k1_router<<<T_TOK / 4, 256, 0, stream>>>(x, wgate, logits, sel, wt, cnt);
  k2_prefix<<<1, 64, 0, stream>>>(cnt, offsets, cursor);
  k3_assign<<<T_TOK / 256, 256, 0, stream>>>(sel, wt, offsets, cursor, slot_token, slot_w,
                                             tok2slot);
  k4_gateup<<<dim3(T_TOK * 2 / 256, IDIM / 128, NE), 512, 0, stream>>>(
      xbf, wgT, wuT, slot_token, offsets, cnt, act);
  k5_down<<<dim3(T_TOK * 2 / 256, HDIM / 256, NE), 512, 0, stream>>>(act, wdT, offsets, cnt, y);
  k6_combine<<<T_TOK * HDIM / 8 / 256, 256, 0, stream>>>(y, tok2slot, slot_w, out);
}

// Round 13
// 654.808 us; speedup vs baseline: 1.1128x; 1.1128x over previous
//
#include <hip/hip_runtime.h>
#include <math.h>

#define T_TOK 8192
#define HDIM 2048
#define IDIM 1024
#define NE 8

typedef __attribute__((ext_vector_type(8))) short short8;
typedef __attribute__((ext_vector_type(4))) float f32x4;
typedef unsigned short u16;

__device__ inline u16 f2bf(float f) {
  unsigned u = __builtin_bit_cast(unsigned, f);
  u += 0x7fffu + ((u >> 16) & 1);  // RNE
  return (u16)(u >> 16);
}
__device__ inline float bf2f(u16 u) {
  unsigned v = (unsigned)u << 16;
  return __builtin_bit_cast(float, v);
}

// async global->LDS, 16B/lane. LDS dest = wave-uniform base + lane*16.
__device__ inline void gl_lds(const u16* g, u16* l) {
  __builtin_amdgcn_global_load_lds((const __attribute__((address_space(1))) unsigned int*)g,
                                   (__attribute__((address_space(3))) unsigned int*)l, 16, 0, 0);
}

// bf16 LDS tiles [row][32] (64B rows); chunk swizzle applied on the GLOBAL
// source address (m173): position p holds global chunk p ^ ((row>>1)&3).
// Frag read of granule g: row*32 + 8*(g ^ ((row>>1)&3)) -> 2-way banks (free).
__device__ inline int rswz(int row, int g) { return row * 32 + 8 * (g ^ ((row >> 1) & 3)); }

// ---------- ws layout ----------
// 0       meta: cnt[8] cursor[8] offsets[8] (u32)
// 256     slot_token u16[2T]  (32 KB)
// 33024   slot_w    f32[2T]   (64 KB)
// 98560   tok2slot  u16[2T]   (32 KB)   -> ends 131328
// 132096  xbf  bf16[T*H]      (33.5 MB)
// ACT     act  bf16[2T*I]     (33.5 MB)  (sel/wt stashed here pre-k4)
// WGT     wgT / wuT           (67 MB)    -> y bf16[2T*H] after k4 (exact fit)
// WDT     wdT                 (33.5 MB)  total 167,904,256 (proven R5)

// ---------------- K01: router + x->bf16 + meta-zero (x read ONCE) ----------------
__global__ __launch_bounds__(256) void k01_router_cvt(const float* __restrict__ x,
                                                      const float* __restrict__ wgate,
                                                      u16* __restrict__ xb,
                                                      float* __restrict__ logits_out,
                                                      char* __restrict__ sel,
                                                      float* __restrict__ wt,
                                                      unsigned* __restrict__ cnt) {
  int wave = threadIdx.x >> 6;
  int lane = threadIdx.x & 63;
  int t = blockIdx.x * 4 + wave;
  float acc[NE];
#pragma unroll
  for (int e = 0; e < NE; ++e) acc[e] = 0.f;
  const float4* xr = (const float4*)(x + (size_t)t * HDIM);
  u16* xbrow = xb + (size_t)t * HDIM;
#pragma unroll
  for (int c = 0; c < HDIM / 256; ++c) {
    float4 xv = xr[c * 64 + lane];
    int h = (c * 64 + lane) * 4;
    // store bf16 copy (same registers, saves a later full re-read of x)
    ushort4 o = make_ushort4(f2bf(xv.x), f2bf(xv.y), f2bf(xv.z), f2bf(xv.w));
    *(ushort4*)(xbrow + h) = o;
    const float xs[4] = {xv.x, xv.y, xv.z, xv.w};
#pragma unroll
    for (int j = 0; j < 4; ++j) {
      const float* wrow = wgate + (size_t)(h + j) * NE;
#pragma unroll
      for (int e = 0; e < NE; ++e) acc[e] += xs[j] * wrow[e];
    }
  }
#pragma unroll
  for (int e = 0; e < NE; ++e) {
    float v = acc[e];
#pragma unroll
    for (int off = 32; off; off >>= 1) v += __shfl_xor(v, off, 64);
    acc[e] = v;
  }
  if (lane == 0) {
    float m = acc[0];
#pragma unroll
    for (int e = 0; e < NE; ++e) {
      logits_out[(size_t)t * NE + e] = acc[e];
      m = fmaxf(m, acc[e]);
    }
    float p[NE];
#pragma unroll
    for (int e = 0; e < NE; ++e) p[e] = expf(acc[e] - m);
    int b0 = 0;
    float v0 = p[0];
#pragma unroll
    for (int e = 1; e < NE; ++e)
      if (p[e] > v0) { v0 = p[e]; b0 = e; }
    int b1 = -1;
    float v1 = -1.f;
#pragma unroll
    for (int e = 0; e < NE; ++e)
      if (e != b0 && p[e] > v1) { v1 = p[e]; b1 = e; }
    float denom = v0 + v1;
    sel[t * 2 + 0] = (char)b0;
    sel[t * 2 + 1] = (char)b1;
    wt[t * 2 + 0] = v0 / denom;
    wt[t * 2 + 1] = v1 / denom;
    atomicAdd(&cnt[b0], 1u);
    atomicAdd(&cnt[b1], 1u);
  }
  if (blockIdx.x == 0 && threadIdx.x >= 8 && threadIdx.x < 24)
    cnt[threadIdx.x] = 0;  // cursor[8] + offsets[8]; cnt itself is atomically built
}

// ---------------- KT: all three weight transposes, one launch ----------------
// dst[n][k] = bf16(src[k][n]) per expert. Flat grid over {wg:512t/e, wu:512t/e, wd:512t/e}x8.
__global__ __launch_bounds__(256) void kt_all(const float* __restrict__ wg, u16* __restrict__ wgT,
                                              const float* __restrict__ wu, u16* __restrict__ wuT,
                                              const float* __restrict__ wd, u16* __restrict__ wdT) {
  __shared__ u16 t[64][72];
  unsigned bid = blockIdx.x;
  // wg/wu tiles: K=HDIM, N=IDIM -> (N/64)*(K/64) = 16*32 = 512 tiles/expert
  // wd tiles:    K=IDIM, N=HDIM -> 32*16 = 512 tiles/expert
  unsigned mat = bid / (512u * NE);       // 0=wg 1=wu 2=wd
  unsigned rem = bid % (512u * NE);
  unsigned e = rem / 512u;
  unsigned tile = rem % 512u;
  int K = (mat == 2) ? IDIM : HDIM;
  int N = (mat == 2) ? HDIM : IDIM;
  const float* src = (mat == 0 ? wg : mat == 1 ? wu : wd) + (size_t)e * K * N;
  u16* dst = (mat == 0 ? wgT : mat == 1 ? wuT : wdT) + (size_t)e * K * N;
  int ntiles_n = N / 64;
  int nb = (int)(tile % ntiles_n) * 64;
  int kb = (int)(tile / ntiles_n) * 64;

  int tid = threadIdx.x;
  int lk = tid >> 4, ln = (tid & 15) * 4;
#pragma unroll
  for (int p = 0; p < 4; ++p) {
    int k = lk + 16 * p;
    float4 v = *(const float4*)(src + (size_t)(kb + k) * N + nb + ln);
    t[ln + 0][k] = f2bf(v.x);
    t[ln + 1][k] = f2bf(v.y);
    t[ln + 2][k] = f2bf(v.z);
    t[ln + 3][k] = f2bf(v.w);
  }
  __syncthreads();
  int n = tid >> 2, c = tid & 3;
  short8 o0 = *(const short8*)&t[n][c * 16];
  short8 o1 = *(const short8*)&t[n][c * 16 + 8];
  u16* d = dst + (size_t)(nb + n) * K + kb + c * 16;
  *(short8*)d = o0;
  *(short8*)(d + 8) = o1;
}

// ---------------- K2 / K3 ----------------
__global__ void k2_prefix(const unsigned* __restrict__ cnt, unsigned* __restrict__ offsets,
                          unsigned* __restrict__ cursor) {
  if (threadIdx.x == 0) {
    unsigned s = 0;
    for (int e = 0; e < NE; ++e) {
      offsets[e] = s;
      s += cnt[e];
    }
  }
  if (threadIdx.x < NE) cursor[threadIdx.x] = 0;
}

__global__ __launch_bounds__(256) void k3_assign(const char* __restrict__ sel,
                                                 const float* __restrict__ wt,
                                                 const unsigned* __restrict__ offsets,
                                                 unsigned* __restrict__ cursor,
                                                 u16* __restrict__ slot_token,
                                                 float* __restrict__ slot_w,
                                                 u16* __restrict__ tok2slot) {
  int t = blockIdx.x * 256 + threadIdx.x;
#pragma unroll
  for (int k = 0; k < 2; ++k) {
    int e = sel[t * 2 + k];
    unsigned p = atomicAdd(&cursor[e], 1u);
    unsigned s = offsets[e] + p;
    slot_token[s] = (u16)t;
    slot_w[s] = wt[t * 2 + k];
    tok2slot[t * 2 + k] = (u16)s;
  }
}

// Bijective XCD swizzle for 64x8x8 = 4096-block grids (8 XCDs, 512/XCD).
// XCD k gets one expert's full block set; bx ascends within a by-column ->
// B-slice (2MB) stays L2-resident across the 16 real row-blocks.
__device__ inline void xcd_decomp(int& bx, int& by, int& be) {
  unsigned bid = blockIdx.x + 64u * (blockIdx.y + 8u * blockIdx.z);
  unsigned swz = (bid & 7u) * 512u + (bid >> 3);
  bx = swz & 63u;
  unsigned rem = swz >> 6;
  by = rem & 7u;
  be = rem >> 3;
}

// ---------------- K4: MFMA gate+up + silu -> bf16 act (R9 structure) ----------------
// tile 128m x 128n, 4 waves (64x64 each), BK=32, ring-3 LDS (72 KB),
// depth-2 prefetch, counted vmcnt, 2 barriers/K-step. Best-measured: 225 us.
__global__ __launch_bounds__(256, 2) void k4_gateup(
    const u16* __restrict__ xb, const u16* __restrict__ wgT, const u16* __restrict__ wuT,
    const u16* __restrict__ slot_token, const unsigned* __restrict__ offsets,
    const unsigned* __restrict__ cnt, u16* __restrict__ act) {
  int bx, by, e;
  xcd_decomp(bx, by, e);
  unsigned n = cnt[e];
  unsigned row0 = (unsigned)bx * 128;
  if (row0 >= n) return;
  unsigned base = offsets[e];
  int col0 = by * 128;

  __shared__ __align__(16) u16 As[3][128 * 32];  // 24 KB
  __shared__ __align__(16) u16 Bg[3][128 * 32];  // 24 KB
  __shared__ __align__(16) u16 Bu[3][128 * 32];  // 24 KB

  int tid = threadIdx.x;
  int w = tid >> 6, l = tid & 63;
  int wr = w >> 1, wc = w & 1;
  int lr = l & 15, g = l >> 4;

  const u16* asrc[2];
  int adst[2];
#pragma unroll
  for (int i = 0; i < 2; ++i) {
    int r = 32 * w + 16 * i + (l >> 2);
    unsigned grow = row0 + (unsigned)r;
    unsigned slot = base + (grow < n ? grow : 0);
    int chunk = (l & 3) ^ ((r >> 1) & 3);
    asrc[i] = xb + (size_t)slot_token[slot] * HDIM + 8 * chunk;
    adst[i] = (32 * w + 16 * i) * 32;
  }
  const u16* bgsrc[2];
  const u16* busrc[2];
  int bdst[2];
#pragma unroll
  for (int i = 0; i < 2; ++i) {
    int nn = 32 * w + 16 * i + (l >> 2);
    int chunk = (l & 3) ^ ((nn >> 1) & 3);
    size_t o = (size_t)e * HDIM * IDIM + (size_t)(col0 + nn) * HDIM + 8 * chunk;
    bgsrc[i] = wgT + o;
    busrc[i] = wuT + o;
    bdst[i] = (32 * w + 16 * i) * 32;
  }

  int afo[4], bfo[4];
#pragma unroll
  for (int mf = 0; mf < 4; ++mf) afo[mf] = rswz(wr * 64 + mf * 16 + lr, g);
#pragma unroll
  for (int nf = 0; nf < 4; ++nf) bfo[nf] = rswz(wc * 64 + nf * 16 + lr, g);

  f32x4 accg[4][4] = {};
  f32x4 accu[4][4] = {};

#define K4_STAGE(k0, buf)                           \
  do {                                              \
    gl_lds(asrc[0] + (k0), &As[buf][adst[0]]);      \
    gl_lds(asrc[1] + (k0), &As[buf][adst[1]]);      \
    gl_lds(bgsrc[0] + (k0), &Bg[buf][bdst[0]]);     \
    gl_lds(bgsrc[1] + (k0), &Bg[buf][bdst[1]]);     \
    gl_lds(busrc[0] + (k0), &Bu[buf][bdst[0]]);     \
    gl_lds(busrc[1] + (k0), &Bu[buf][bdst[1]]);     \
  } while (0)

  K4_STAGE(0, 0);
  K4_STAGE(32, 1);  // 12 loads in flight

  const int NK = HDIM / 32;
  int c = 0, sb = 2;
  for (int kt = 0; kt < NK; ++kt) {
    if (kt + 2 < NK) {
      K4_STAGE((kt + 2) * 32, sb);                       // 18 in flight
      asm volatile("s_waitcnt vmcnt(12)" ::: "memory");  // tile kt landed
    } else if (kt + 1 < NK) {
      asm volatile("s_waitcnt vmcnt(6)" ::: "memory");
    } else {
      asm volatile("s_waitcnt vmcnt(0)" ::: "memory");
    }
    __builtin_amdgcn_s_barrier();

    short8 af[4];
#pragma unroll
    for (int mf = 0; mf < 4; ++mf) af[mf] = *(const short8*)&As[c][afo[mf]];
#pragma unroll
    for (int nf = 0; nf < 4; ++nf) {
      short8 bgf = *(const short8*)&Bg[c][bfo[nf]];
      short8 buf = *(const short8*)&Bu[c][bfo[nf]];
#pragma unroll
      for (int mf = 0; mf < 4; ++mf) {
        accg[mf][nf] = __builtin_amdgcn_mfma_f32_16x16x32_bf16(af[mf], bgf, accg[mf][nf], 0, 0, 0);
        accu[mf][nf] = __builtin_amdgcn_mfma_f32_16x16x32_bf16(af[mf], buf, accu[mf][nf], 0, 0, 0);
      }
    }
    __builtin_amdgcn_s_barrier();
    c = (c == 2) ? 0 : c + 1;
    sb = (sb == 2) ? 0 : sb + 1;
  }
#undef K4_STAGE

  unsigned rows_left = n - row0;
#pragma unroll
  for (int mf = 0; mf < 4; ++mf)
#pragma unroll
    for (int nf = 0; nf < 4; ++nf)
#pragma unroll
      for (int j = 0; j < 4; ++j) {
        int rin = wr * 64 + mf * 16 + 4 * g + j;
        if ((unsigned)rin < rows_left) {
          size_t s = base + row0 + rin;
          int col = col0 + wc * 64 + nf * 16 + lr;
          float gg = accg[mf][nf][j];
          float uu = accu[mf][nf][j];
          float v = (gg / (1.f + expf(-gg))) * uu;
          act[s * IDIM + col] = f2bf(v);
        }
      }
}

// ---------------- K5: MFMA down -> bf16 y (R9 structure) ----------------
// tile 128m x 256n, 4 waves (64x128 each), BK=32, ring-3, depth-2, counted vmcnt.
__global__ __launch_bounds__(256, 2) void k5_down(
    const u16* __restrict__ act, const u16* __restrict__ wdT,
    const unsigned* __restrict__ offsets, const unsigned* __restrict__ cnt,
    u16* __restrict__ y) {
  int bx, by, e;
  xcd_decomp(bx, by, e);
  unsigned n = cnt[e];
  unsigned row0 = (unsigned)bx * 128;
  if (row0 >= n) return;
  unsigned base = offsets[e];
  int col0 = by * 256;

  __shared__ __align__(16) u16 As[3][128 * 32];  // 24 KB
  __shared__ __align__(16) u16 Bs[3][256 * 32];  // 48 KB

  int tid = threadIdx.x;
  int w = tid >> 6, l = tid & 63;
  int wr = w >> 1, wc = w & 1;
  int lr = l & 15, g = l >> 4;

  const u16* asrc[2];
  int adst[2];
#pragma unroll
  for (int i = 0; i < 2; ++i) {
    int r = 32 * w + 16 * i + (l >> 2);
    unsigned grow = row0 + (unsigned)r;
    unsigned slot = base + (grow < n ? grow : 0);
    int chunk = (l & 3) ^ ((r >> 1) & 3);
    asrc[i] = act + (size_t)slot * IDIM + 8 * chunk;
    adst[i] = (32 * w + 16 * i) * 32;
  }
  const u16* bsrc[4];
  int bdst[4];
#pragma unroll
  for (int i = 0; i < 4; ++i) {
    int nn = 64 * w + 16 * i + (l >> 2);
    int chunk = (l & 3) ^ ((nn >> 1) & 3);
    bsrc[i] = wdT + (size_t)e * IDIM * HDIM + (size_t)(col0 + nn) * IDIM + 8 * chunk;
    bdst[i] = (64 * w + 16 * i) * 32;
  }

  int afo[4], bfo[8];
#pragma unroll
  for (int mf = 0; mf < 4; ++mf) afo[mf] = rswz(wr * 64 + mf * 16 + lr, g);
#pragma unroll
  for (int nf = 0; nf < 8; ++nf) bfo[nf] = rswz(wc * 128 + nf * 16 + lr, g);

  f32x4 acc[4][8] = {};

#define K5_STAGE(k0, buf)                        \
  do {                                           \
    gl_lds(asrc[0] + (k0), &As[buf][adst[0]]);   \
    gl_lds(asrc[1] + (k0), &As[buf][adst[1]]);   \
    gl_lds(bsrc[0] + (k0), &Bs[buf][bdst[0]]);   \
    gl_lds(bsrc[1] + (k0), &Bs[buf][bdst[1]]);   \
    gl_lds(bsrc[2] + (k0), &Bs[buf][bdst[2]]);   \
    gl_lds(bsrc[3] + (k0), &Bs[buf][bdst[3]]);   \
  } while (0)

  K5_STAGE(0, 0);
  K5_STAGE(32, 1);

  const int NK = IDIM / 32;
  int c = 0, sb = 2;
  for (int kt = 0; kt < NK; ++kt) {
    if (kt + 2 < NK) {
      K5_STAGE((kt + 2) * 32, sb);
      asm volatile("s_waitcnt vmcnt(12)" ::: "memory");
    } else if (kt + 1 < NK) {
      asm volatile("s_waitcnt vmcnt(6)" ::: "memory");
    } else {
      asm volatile("s_waitcnt vmcnt(0)" ::: "memory");
    }
    __builtin_amdgcn_s_barrier();

    short8 af[4];
#pragma unroll
    for (int mf = 0; mf < 4; ++mf) af[mf] = *(const short8*)&As[c][afo[mf]];
#pragma unroll
    for (int nf = 0; nf < 8; ++nf) {
      short8 bd = *(const short8*)&Bs[c][bfo[nf]];
#pragma unroll
      for (int mf = 0; mf < 4; ++mf)
        acc[mf][nf] = __builtin_amdgcn_mfma_f32_16x16x32_bf16(af[mf], bd, acc[mf][nf], 0, 0, 0);
    }
    __builtin_amdgcn_s_barrier();
    c = (c == 2) ? 0 : c + 1;
    sb = (sb == 2) ? 0 : sb + 1;
  }
#undef K5_STAGE

  unsigned rows_left = n - row0;
#pragma unroll
  for (int mf = 0; mf < 4; ++mf)
#pragma unroll
    for (int j = 0; j < 4; ++j) {
      int rin = wr * 64 + mf * 16 + 4 * g + j;
      if ((unsigned)rin < rows_left) {
        size_t s = base + row0 + rin;
        u16* yrow = y + s * HDIM + col0 + wc * 128 + lr;
#pragma unroll
        for (int nf = 0; nf < 8; ++nf) yrow[nf * 16] = f2bf(acc[mf][nf][j]);
      }
    }
}

// ---------------- K6: combine out[t] = w0*y[s0] + w1*y[s1] ----------------
__global__ __launch_bounds__(512) void k6_combine(const u16* __restrict__ y,
                                                  const u16* __restrict__ tok2slot,
                                                  const float* __restrict__ slot_w,
                                                  float* __restrict__ out) {
  unsigned idx = blockIdx.x * 512 + threadIdx.x;  // one per 8 elems
  int t = idx >> 8;                               // HDIM/8 = 256 chunks per row
  int off = (idx & 255) * 8;
  int s0 = tok2slot[t * 2 + 0];
  int s1 = tok2slot[t * 2 + 1];
  float w0 = slot_w[s0];
  float w1 = slot_w[s1];
  short8 a = *(const short8*)(y + (size_t)s0 * HDIM + off);
  short8 b = *(const short8*)(y + (size_t)s1 * HDIM + off);
  float* o = out + (size_t)t * HDIM + off;
  float4 o0, o1;
  o0.x = w0 * bf2f((u16)a[0]) + w1 * bf2f((u16)b[0]);
  o0.y = w0 * bf2f((u16)a[1]) + w1 * bf2f((u16)b[1]);
  o0.z = w0 * bf2f((u16)a[2]) + w1 * bf2f((u16)b[2]);
  o0.w = w0 * bf2f((u16)a[3]) + w1 * bf2f((u16)b[3]);
  o1.x = w0 * bf2f((u16)a[4]) + w1 * bf2f((u16)b[4]);
  o1.y = w0 * bf2f((u16)a[5]) + w1 * bf2f((u16)b[5]);
  o1.z = w0 * bf2f((u16)a[6]) + w1 * bf2f((u16)b[6]);
  o1.w = w0 * bf2f((u16)a[7]) + w1 * bf2f((u16)b[7]);
  *(float4*)o = o0;
  *(float4*)(o + 4) = o1;
}

extern "C" void kernel_launch(void* const* d_in, const int* in_sizes, int n_in,
                              void* d_out, int out_size, void* d_ws, size_t ws_size,
                              hipStream_t stream) {
  const float* x = (const float*)d_in[0];
  const float* wgate = (const float*)d_in[1];
  const float* wg = (const float*)d_in[2];
  const float* wu = (const float*)d_in[3];
  const float* wd = (const float*)d_in[4];
  float* out = (float*)d_out;
  float* logits = out + (size_t)T_TOK * HDIM;

  const size_t XBF_OFF = 132096;
  const size_t ACT_OFF = XBF_OFF + (size_t)T_TOK * HDIM * 2;
  const size_t WGT_OFF = ACT_OFF + (size_t)2 * T_TOK * IDIM * 2;
  const size_t WUT_OFF = WGT_OFF + (size_t)NE * HDIM * IDIM * 2;
  const size_t WDT_OFF = WUT_OFF + (size_t)NE * HDIM * IDIM * 2;
  const size_t NEED_T3 = WDT_OFF + (size_t)NE * IDIM * HDIM * 2;  // 167,904,256 (proven R5)
  if (ws_size < NEED_T3) return;  // loud failure

  char* ws = (char*)d_ws;
  unsigned* meta = (unsigned*)ws;
  unsigned* cnt = meta + 0;
  unsigned* cursor = meta + 8;
  unsigned* offsets = meta + 16;
  u16* slot_token = (u16*)(ws + 256);
  float* slot_w = (float*)(ws + 33024);
  u16* tok2slot = (u16*)(ws + 98560);
  u16* xbf = (u16*)(ws + XBF_OFF);
  u16* act = (u16*)(ws + ACT_OFF);
  u16* wgT = (u16*)(ws + WGT_OFF);
  u16* wuT = (u16*)(ws + WUT_OFF);
  u16* wdT = (u16*)(ws + WDT_OFF);
  u16* y = (u16*)(ws + WGT_OFF);  // reuses wgT+wuT (dead after k4)
  char* sel = (char*)act;         // dead before k4 writes act
  float* wt = (float*)((char*)act + 16384);

  // cnt must be zero before k01's atomics: zero it with a tiny leading kernel-free
  // trick is not possible; use k2-style: hipMemsetAsync is allowed (async, stream).
  hipMemsetAsync(cnt, 0, 32, stream);
  k01_router_cvt<<<T_TOK / 4, 256, 0, stream>>>(x, wgate, xbf, logits, sel, wt, cnt);
  kt_all<<<3 * 512 * NE, 256, 0, stream>>>(wg, wgT, wu, wuT, wd, wdT);
  k2_prefix<<<1, 64, 0, stream>>>(cnt, offsets, cursor);
  k3_assign<<<T_TOK / 256, 256, 0, stream>>>(sel, wt, offsets, cursor, slot_token, slot_w,
                                             tok2slot);
  k4_gateup<<<dim3(T_TOK / 128, IDIM / 128, NE), 256, 0, stream>>>(xbf, wgT, wuT, slot_token,
                                                                   offsets, cnt, act);
  k5_down<<<dim3(T_TOK / 128, HDIM / 256, NE), 256, 0, stream>>>(act, wdT, offsets, cnt, y);
  k6_combine<<<T_TOK * HDIM / 8 / 512, 512, 0, stream>>>(y, tok2slot, slot_w, out);
}